// Round 1
// 1046.021 us; speedup vs baseline: 1.0281x; 1.0281x over previous
//
#include <hip/hip_runtime.h>
#include <stdint.h>
#include <type_traits>

// Problem constants: B=32, L=4096, C=512, H=8, S=8, NW=512, D=64
// M = B*L = 131072 rows. I/O fp32 (per reference); internal compute bf16.

typedef unsigned short ushort_t;
typedef __bf16 v8bf __attribute__((ext_vector_type(8)));
typedef float v4f __attribute__((ext_vector_type(4)));

__device__ __forceinline__ ushort_t f2bf(float f) {
  unsigned int u = __float_as_uint(f);
  u = u + 0x7fffu + ((u >> 16) & 1u);   // RNE
  return (ushort_t)(u >> 16);
}

// ---------------- prep: transpose fp32 weights -> bf16 B^T, fused qkv bias ---
__global__ __launch_bounds__(256) void prep_kernel(
    const float* __restrict__ Wq, const float* __restrict__ Wk,
    const float* __restrict__ Wv, const float* __restrict__ Wp,
    const float* __restrict__ bq, const float* __restrict__ bk,
    const float* __restrict__ bv,
    ushort_t* __restrict__ WTqkv, ushort_t* __restrict__ WTp,
    float* __restrict__ bqkvf)
{
  int idx = blockIdx.x * 256 + threadIdx.x;
  if (idx < 786432) {                       // WTqkv[n][k] = W_{q,k,v}[k][n&511]
    int n = idx % 1536;
    int k = idx / 1536;
    const float* W = (n < 512) ? Wq : (n < 1024) ? Wk : Wv;
    WTqkv[(size_t)n * 512 + k] = f2bf(W[k * 512 + (n & 511)]);
  } else if (idx < 1048576) {               // WTp[n][k] = Wp[k][n]
    int j = idx - 786432;
    int n = j & 511;
    int k = j >> 9;
    WTp[(size_t)n * 512 + k] = f2bf(Wp[k * 512 + n]);
  } else if (idx < 1050112) {               // fused qkv bias (fp32)
    int n = idx - 1048576;
    const float* bb = (n < 512) ? bq : (n < 1024) ? bk : bv;
    bqkvf[n] = bb[n & 511];
  }
}

// ---------------- convert fp32 x -> bf16, roll(x,-4) folded into row remap ---
__global__ __launch_bounds__(256) void convert_roll_kernel(
    const float* __restrict__ x, ushort_t* __restrict__ xb)
{
  const int t = blockIdx.x * 256 + threadIdx.x;   // 8,388,608 threads
  const int m = t >> 6;                           // dest row (rolled space)
  const int ch = t & 63;                          // 8-element chunk
  const int b = m >> 12;
  const int r = m & 4095;
  const int src = (b << 12) | ((r + 4) & 4095);
  const float4* p = (const float4*)(x + (size_t)src * 512 + ch * 8);
  float4 a0 = p[0], a1 = p[1];
  uint4 o;
  o.x = (unsigned)f2bf(a0.x) | ((unsigned)f2bf(a0.y) << 16);
  o.y = (unsigned)f2bf(a0.z) | ((unsigned)f2bf(a0.w) << 16);
  o.z = (unsigned)f2bf(a1.x) | ((unsigned)f2bf(a1.y) << 16);
  o.w = (unsigned)f2bf(a1.z) | ((unsigned)f2bf(a1.w) << 16);
  *(uint4*)(xb + (size_t)m * 512 + ch * 8) = o;
}

// ============================================================================
// 256x256 8-phase bf16 GEMM (T1+T2+T3+T4+T5 per §5.5 catalog).
// 512 threads = 8 waves. K=512 fixed -> KT=8 tiles of BK=64, 4 iterations of
// 2 K-tiles / 8 phases. LDS 128 KiB: A[2buf][2half][128][64] + B likewise.
// Swizzle: elem k -> k ^ ((row&7)<<3), realized as inverse-permuted GLOBAL
// source for global_load_lds (linear LDS dest) + swizzled ds_read (rule #21).
// Counted vmcnt(4) at phases 4/8 BEFORE the barrier (cross-wave safety);
// vmcnt(0) on the last iteration's phase 4 (tail halves still in flight).
// ============================================================================

#define SB() __builtin_amdgcn_sched_barrier(0)

__device__ __forceinline__ void stage_half(
    const ushort_t* __restrict__ G, ushort_t* lds_b, int boff,
    int kt, int half, int rowbase, int tid)
{
  // LDS dest region: [buf=kt&1][half] -> 8192 elements (128 rows x 64 k)
  ushort_t* Lb = lds_b + boff + (((kt & 1) << 1) + half) * 8192;
  const int rb = rowbase + (half << 7);
#pragma unroll
  for (int i = 0; i < 2; ++i) {
    const int c = tid + (i << 9);             // chunk id 0..1023
    const int row = c >> 3;
    const int slot = c & 7;
    const int scol = (slot ^ (row & 7)) << 3; // inverse-swizzled source column
    const ushort_t* src = G + (size_t)(rb + row) * 512 + (kt << 6) + scol;
    __builtin_amdgcn_global_load_lds(
        (const __attribute__((address_space(1))) void*)src,
        (__attribute__((address_space(3))) void*)(Lb + ((size_t)c << 3)),
        16, 0, 0);
  }
}

__device__ __forceinline__ void mfma_quad(
    v4f (&accq)[2][4], const v8bf (&af)[2][2], const v8bf (&bq)[4][2])
{
#pragma unroll
  for (int mi = 0; mi < 2; ++mi)
#pragma unroll
    for (int ni = 0; ni < 4; ++ni)
#pragma unroll
      for (int kk = 0; kk < 2; ++kk)
        accq[mi][ni] = __builtin_amdgcn_mfma_f32_16x16x32_bf16(
            af[mi][kk], bq[ni][kk], accq[mi][ni], 0, 0, 0);
}

template<int LDC, int GN, bool ROLL_C, typename OutT>
__global__ __launch_bounds__(512, 2) void gemm256(
    const ushort_t* __restrict__ A, const ushort_t* __restrict__ BT,
    const float* __restrict__ bias, OutT* __restrict__ C)
{
  extern __shared__ ushort_t lds[];           // 131072 B: A at 0, B at 32768 el

  const int tid = threadIdx.x;
  const int l   = tid & 63;
  const int wv  = tid >> 6;                   // 0..7
  const int wr  = wv >> 1;                    // quadrant row chunk 0..3 (x32)
  const int wc  = wv & 1;                     // quadrant col chunk 0..1 (x64)
  const int fr  = l & 15;
  const int fq  = l >> 4;

  // T1: XCD-aware bijective swizzle (NWG % 8 == 0 for both instantiations)
  constexpr int NWG = GN * 512;               // M tiles = 131072/256 = 512
  const int bid = blockIdx.x;
  const int swz = (bid & 7) * (NWG >> 3) + (bid >> 3);
  const int m0 = (swz / GN) * 256;
  const int n0 = (swz % GN) * 256;

  const int arow = wr * 32 + fr;              // A row within half (mi=0)
  const int brow = wc * 64 + fr;              // B row within half (ni=0)
  const int kswz = (fr & 7) << 3;             // T2 read-side XOR swizzle
  const int kb   = fq << 3;

#define LDA_FRAGS(bufq) do { \
  _Pragma("unroll") for (int mi = 0; mi < 2; ++mi) \
  _Pragma("unroll") for (int kk = 0; kk < 2; ++kk) \
    af[mi][kk] = *(const v8bf*)(lds + (bufq) * 8192 + \
        (arow + mi * 16) * 64 + ((kk * 32 + kb) ^ kswz)); \
} while (0)
#define LDB_FRAGS(qn, bufq) do { \
  _Pragma("unroll") for (int ni = 0; ni < 4; ++ni) \
  _Pragma("unroll") for (int kk = 0; kk < 2; ++kk) \
    bfr[qn][ni][kk] = *(const v8bf*)(lds + 32768 + (bufq) * 8192 + \
        (brow + ni * 16) * 64 + ((kk * 32 + kb) ^ kswz)); \
} while (0)
#define MFMA_PHASE(QM, QN) do { \
  SB(); __builtin_amdgcn_s_barrier(); SB(); \
  __builtin_amdgcn_s_setprio(1); \
  mfma_quad(acc[QM][QN], af, bfr[QN]); \
  __builtin_amdgcn_s_setprio(0); \
  SB(); } while (0)
#define ENDBAR() do { __builtin_amdgcn_s_barrier(); SB(); } while (0)

  v4f acc[2][2][2][4];                        // [Qm][Qn][mi][ni]
#pragma unroll
  for (int a = 0; a < 2; ++a)
#pragma unroll
    for (int b = 0; b < 2; ++b)
#pragma unroll
      for (int m = 0; m < 2; ++m)
#pragma unroll
        for (int n = 0; n < 4; ++n)
          acc[a][b][m][n] = (v4f){0.f, 0.f, 0.f, 0.f};

  // ---- prologue: 6 half-tiles (tile0 complete + tile1 h0s), wait all-but-4
  stage_half(A,  lds, 0,     0, 0, m0, tid);  // A0h0
  stage_half(BT, lds, 32768, 0, 0, n0, tid);  // B0h0
  stage_half(A,  lds, 0,     0, 1, m0, tid);  // A0h1
  stage_half(BT, lds, 32768, 0, 1, n0, tid);  // B0h1
  stage_half(A,  lds, 0,     1, 0, m0, tid);  // A1h0
  stage_half(BT, lds, 32768, 1, 0, n0, tid);  // B1h0
  SB();
  asm volatile("s_waitcnt vmcnt(4)" ::: "memory");  // tile0 landed
  __builtin_amdgcn_s_barrier();
  SB();

  for (int t = 0; t < 4; ++t) {               // 2 K-tiles per iteration
    const bool more = (t < 3);
    const int o = 2 * t + 1;
    v8bf af[2][2];                            // current A half [mi][kk]
    v8bf bfr[2][4][2];                        // both B halves [Qn][ni][kk]

    // ---- phase 1: Q(0,0) of tile 2t (buf0); stage A(buf1,h1) <- tile o
    LDA_FRAGS(0);
    LDB_FRAGS(0, 0);
    stage_half(A, lds, 0, o, 1, m0, tid);
    MFMA_PHASE(0, 0);
    ENDBAR();
    // ---- phase 2: Q(0,1); stage B(buf1,h1) <- tile o
    LDB_FRAGS(1, 1);
    stage_half(BT, lds, 32768, o, 1, n0, tid);
    MFMA_PHASE(0, 1);
    ENDBAR();
    // ---- phase 3: Q(1,0); stage A(buf0,h0) <- tile 2t+2
    LDA_FRAGS(1);
    if (more) stage_half(A, lds, 0, o + 1, 0, m0, tid);
    MFMA_PHASE(1, 0);
    ENDBAR();
    // ---- phase 4: Q(1,1); stage B(buf0,h0) <- tile 2t+2; counted vmcnt
    if (more) stage_half(BT, lds, 32768, o + 1, 0, n0, tid);
    MFMA_PHASE(1, 1);
    if (t == 3) asm volatile("s_waitcnt vmcnt(0)" ::: "memory");
    else        asm volatile("s_waitcnt vmcnt(4)" ::: "memory");
    ENDBAR();
    // ---- phase 5: Q(0,0) of tile o (buf1); stage A(buf0,h1) <- tile 2t+2
    LDA_FRAGS(2);
    LDB_FRAGS(0, 2);
    if (more) stage_half(A, lds, 0, o + 1, 1, m0, tid);
    MFMA_PHASE(0, 0);
    ENDBAR();
    // ---- phase 6: Q(0,1); stage B(buf0,h1) <- tile 2t+2
    LDB_FRAGS(1, 3);
    if (more) stage_half(BT, lds, 32768, o + 1, 1, n0, tid);
    MFMA_PHASE(0, 1);
    ENDBAR();
    // ---- phase 7: Q(1,0); stage A(buf1,h0) <- tile 2t+3
    LDA_FRAGS(3);
    if (more) stage_half(A, lds, 0, o + 2, 0, m0, tid);
    MFMA_PHASE(1, 0);
    ENDBAR();
    // ---- phase 8: Q(1,1); stage B(buf1,h0) <- tile 2t+3; counted vmcnt
    if (more) stage_half(BT, lds, 32768, o + 2, 0, n0, tid);
    MFMA_PHASE(1, 1);
    asm volatile("s_waitcnt vmcnt(4)" ::: "memory");
    ENDBAR();
  }

  // ---- epilogue: C/D layout col = lane&15, row = (lane>>4)*4 + r [m89/m91]
#pragma unroll
  for (int Qm = 0; Qm < 2; ++Qm)
#pragma unroll
    for (int Qn = 0; Qn < 2; ++Qn)
#pragma unroll
      for (int mi = 0; mi < 2; ++mi)
#pragma unroll
        for (int ni = 0; ni < 4; ++ni) {
          const int col = n0 + Qn * 128 + wc * 64 + ni * 16 + fr;
          const float bv = bias[col];
#pragma unroll
          for (int r = 0; r < 4; ++r) {
            int row = m0 + Qm * 128 + wr * 32 + mi * 16 + fq * 4 + r;
            if (ROLL_C) row = (row & ~4095) | ((row + 4) & 4095);
            const float val = acc[Qm][Qn][mi][ni][r] + bv;
            if constexpr (std::is_same_v<OutT, float>)
              C[(size_t)row * LDC + col] = val;
            else
              C[(size_t)row * LDC + col] = f2bf(val);
          }
        }

#undef LDA_FRAGS
#undef LDB_FRAGS
#undef MFMA_PHASE
#undef ENDBAR
}

// ---------------- attention: one wave per (batch, window, head) --------------
// qkv layout: [B*L][1536] rolled rows; cols 0..511=Q, 512..1023=K, 1024..1535=V
__device__ __forceinline__ void unpack8(uint4 v, float* f) {
  f[0] = __uint_as_float(v.x << 16); f[1] = __uint_as_float(v.x & 0xffff0000u);
  f[2] = __uint_as_float(v.y << 16); f[3] = __uint_as_float(v.y & 0xffff0000u);
  f[4] = __uint_as_float(v.z << 16); f[5] = __uint_as_float(v.z & 0xffff0000u);
  f[6] = __uint_as_float(v.w << 16); f[7] = __uint_as_float(v.w & 0xffff0000u);
}

__global__ __launch_bounds__(256) void attn_kernel(
    const ushort_t* __restrict__ qkv, const float* __restrict__ bias_table,
    ushort_t* __restrict__ attout)
{
  __shared__ float btab[120];                 // (2S-1) x H fp32
  if (threadIdx.x < 120) btab[threadIdx.x] = bias_table[threadIdx.x];
  __syncthreads();

  const int l  = threadIdx.x & 63;
  const int wv = threadIdx.x >> 6;
  const int u  = blockIdx.x * 4 + wv;         // window-head id
  const int b  = u >> 12;                     // NW*H = 4096
  const int w  = (u >> 3) & 511;
  const int h  = u & 7;
  const int i  = l >> 3;                      // query row in window
  const int c  = l & 7;                       // 8-element d-chunk

  const size_t rowi = (size_t)(b << 12) + (w << 3) + i;
  const ushort_t* pq = qkv + rowi * 1536 + h * 64 + c * 8;
  uint4 q8 = *(const uint4*)pq;
  uint4 k8 = *(const uint4*)(pq + 512);
  uint4 v8 = *(const uint4*)(pq + 1024);

  float qf[8];
  unpack8(q8, qf);

  // energy[i][j], j = (i+t)&7 held in e[t]; rotation via shfl (l+8t)&63
  float e[8];
#pragma unroll
  for (int t = 0; t < 8; ++t) {
    const int src = (l + 8 * t) & 63;
    uint4 kc;
    kc.x = __shfl((int)k8.x, src); kc.y = __shfl((int)k8.y, src);
    kc.z = __shfl((int)k8.z, src); kc.w = __shfl((int)k8.w, src);
    float kf[8]; unpack8(kc, kf);
    float s = 0.f;
#pragma unroll
    for (int d = 0; d < 8; ++d) s = fmaf(qf[d], kf[d], s);
    s += __shfl_xor(s, 1);                    // butterfly over c (3 steps)
    s += __shfl_xor(s, 2);
    s += __shfl_xor(s, 4);
    e[t] = s;
  }

  const float scale = 0.044194173824159216f;  // 1/sqrt(C=512)
#pragma unroll
  for (int t = 0; t < 8; ++t) {
    const int j = (i + t) & 7;
    float ev = e[t] * scale + btab[(j - i + 7) * 8 + h];
    if (w == 511 && ((i < 4) != (j < 4))) ev -= 100.f;  // shift mask
    e[t] = ev;
  }

  float mx = e[0];
#pragma unroll
  for (int t = 1; t < 8; ++t) mx = fmaxf(mx, e[t]);
  float p[8], sum = 0.f;
#pragma unroll
  for (int t = 0; t < 8; ++t) { p[t] = __expf(e[t] - mx); sum += p[t]; }
  const float inv = __fdividef(1.f, sum);

  float of[8] = {0.f, 0.f, 0.f, 0.f, 0.f, 0.f, 0.f, 0.f};
#pragma unroll
  for (int t = 0; t < 8; ++t) {
    const int src = (l + 8 * t) & 63;
    uint4 vc;
    vc.x = __shfl((int)v8.x, src); vc.y = __shfl((int)v8.y, src);
    vc.z = __shfl((int)v8.z, src); vc.w = __shfl((int)v8.w, src);
    float vf[8]; unpack8(vc, vf);
    const float a = p[t] * inv;
#pragma unroll
    for (int d = 0; d < 8; ++d) of[d] = fmaf(a, vf[d], of[d]);
  }

  uint4 o;
  o.x = (unsigned)f2bf(of[0]) | ((unsigned)f2bf(of[1]) << 16);
  o.y = (unsigned)f2bf(of[2]) | ((unsigned)f2bf(of[3]) << 16);
  o.z = (unsigned)f2bf(of[4]) | ((unsigned)f2bf(of[5]) << 16);
  o.w = (unsigned)f2bf(of[6]) | ((unsigned)f2bf(of[7]) << 16);
  *(uint4*)(attout + rowi * 512 + h * 64 + c * 8) = o;
}

// ---------------- launcher ---------------------------------------------------
extern "C" void kernel_launch(void* const* d_in, const int* in_sizes, int n_in,
                              void* d_out, int out_size, void* d_ws, size_t ws_size,
                              hipStream_t stream) {
  (void)in_sizes; (void)n_in; (void)out_size; (void)ws_size;
  const float* x  = (const float*)d_in[0];
  const float* Wq = (const float*)d_in[1];
  const float* bq = (const float*)d_in[2];
  const float* Wk = (const float*)d_in[3];
  const float* bk = (const float*)d_in[4];
  const float* Wv = (const float*)d_in[5];
  const float* bv = (const float*)d_in[6];
  const float* Wp = (const float*)d_in[7];
  const float* bp = (const float*)d_in[8];
  const float* bt = (const float*)d_in[9];

  char* ws = (char*)d_ws;
  ushort_t* qkv    = (ushort_t*)(ws);                    // 131072*1536*2 = 402,653,184
  ushort_t* xb     = (ushort_t*)(ws + 402653184ull);     // 131072*512*2  = 134,217,728
  ushort_t* attout = xb;                                 // reuse: xb dead after QKV GEMM
  ushort_t* WTqkv  = (ushort_t*)(ws + 536870912ull);     // 1536*512*2
  ushort_t* WTp    = (ushort_t*)(ws + 538443776ull);     // 512*512*2
  float*    bqkvf  = (float*)  (ws + 538968064ull);      // 1536*4

  prep_kernel<<<4103, 256, 0, stream>>>(Wq, Wk, Wv, Wp, bq, bk, bv,
                                        WTqkv, WTp, bqkvf);
  // fp32 -> bf16 with roll(x,-4) folded in
  convert_roll_kernel<<<32768, 256, 0, stream>>>(x, xb);
  // QKV projection (bf16 out): M=131072, N=1536, K=512 -> 3072 blocks
  gemm256<1536, 6, false, ushort_t><<<3072, 512, 131072, stream>>>(
      xb, WTqkv, bqkvf, qkv);
  // windowed attention
  attn_kernel<<<32768, 256, 0, stream>>>(qkv, bt, attout);
  // output projection, fp32 out, roll(+4) folded into C-row remap
  gemm256<512, 2, true, float><<<1024, 512, 131072, stream>>>(
      attout, WTp, bp, (float*)d_out);
}

// Round 2
// 1045.015 us; speedup vs baseline: 1.0291x; 1.0010x over previous
//
#include <hip/hip_runtime.h>
#include <stdint.h>
#include <type_traits>

// Problem constants: B=32, L=4096, C=512, H=8, S=8, NW=512, D=64
// M = B*L = 131072 rows. I/O fp32 (per reference); internal compute bf16.

typedef unsigned short ushort_t;
typedef __bf16 v8bf __attribute__((ext_vector_type(8)));
typedef float v4f __attribute__((ext_vector_type(4)));

__device__ __forceinline__ ushort_t f2bf(float f) {
  unsigned int u = __float_as_uint(f);
  u = u + 0x7fffu + ((u >> 16) & 1u);   // RNE
  return (ushort_t)(u >> 16);
}

// ---------------- prep: transpose fp32 weights -> bf16 B^T, fused qkv bias ---
__global__ __launch_bounds__(256) void prep_kernel(
    const float* __restrict__ Wq, const float* __restrict__ Wk,
    const float* __restrict__ Wv, const float* __restrict__ Wp,
    const float* __restrict__ bq, const float* __restrict__ bk,
    const float* __restrict__ bv,
    ushort_t* __restrict__ WTqkv, ushort_t* __restrict__ WTp,
    float* __restrict__ bqkvf)
{
  int idx = blockIdx.x * 256 + threadIdx.x;
  if (idx < 786432) {                       // WTqkv[n][k] = W_{q,k,v}[k][n&511]
    int n = idx % 1536;
    int k = idx / 1536;
    const float* W = (n < 512) ? Wq : (n < 1024) ? Wk : Wv;
    WTqkv[(size_t)n * 512 + k] = f2bf(W[k * 512 + (n & 511)]);
  } else if (idx < 1048576) {               // WTp[n][k] = Wp[k][n]
    int j = idx - 786432;
    int n = j & 511;
    int k = j >> 9;
    WTp[(size_t)n * 512 + k] = f2bf(Wp[k * 512 + n]);
  } else if (idx < 1050112) {               // fused qkv bias (fp32)
    int n = idx - 1048576;
    const float* bb = (n < 512) ? bq : (n < 1024) ? bk : bv;
    bqkvf[n] = bb[n & 511];
  }
}

// ---------------- convert fp32 x -> bf16, roll(x,-4) folded into row remap ---
__global__ __launch_bounds__(256) void convert_roll_kernel(
    const float* __restrict__ x, ushort_t* __restrict__ xb)
{
  const int t = blockIdx.x * 256 + threadIdx.x;   // 8,388,608 threads
  const int m = t >> 6;                           // dest row (rolled space)
  const int ch = t & 63;                          // 8-element chunk
  const int b = m >> 12;
  const int r = m & 4095;
  const int src = (b << 12) | ((r + 4) & 4095);
  const float4* p = (const float4*)(x + (size_t)src * 512 + ch * 8);
  float4 a0 = p[0], a1 = p[1];
  uint4 o;
  o.x = (unsigned)f2bf(a0.x) | ((unsigned)f2bf(a0.y) << 16);
  o.y = (unsigned)f2bf(a0.z) | ((unsigned)f2bf(a0.w) << 16);
  o.z = (unsigned)f2bf(a1.x) | ((unsigned)f2bf(a1.y) << 16);
  o.w = (unsigned)f2bf(a1.z) | ((unsigned)f2bf(a1.w) << 16);
  *(uint4*)(xb + (size_t)m * 512 + ch * 8) = o;
}

// ============================================================================
// 256x256 8-phase bf16 GEMM (T1+T2+T3+T4+T5 per §5.5 catalog).
// 512 threads = 8 waves. K=512 fixed -> KT=8 tiles of BK=64, 4 iterations of
// 2 K-tiles / 8 phases. LDS 128 KiB: A[2buf][2half][128][64] + B likewise.
// Swizzle: elem k -> k ^ ((row&7)<<3), realized as inverse-permuted GLOBAL
// source for global_load_lds (linear LDS dest) + swizzled ds_read (rule #21).
// Counted vmcnt(4) at phases 4/8 BEFORE the barrier (cross-wave safety);
// vmcnt(0) on the last iteration's phase 4 (tail halves still in flight).
//
// R1 finding: extern-shared hides the 128 KiB from the compiler's occupancy
// heuristic -> it capped VGPRs at 128 and spilled ~16 regs (WRITE_SIZE
// overshoot +101 MB = 33 KB/block scratch write-back). LDS already limits us
// to 1 block/CU = 2 waves/SIMD, so pin waves_per_eu to (2,2): full 256-VGPR
// budget, live set (~165) fits, zero spills.
// ============================================================================

#define SB() __builtin_amdgcn_sched_barrier(0)

__device__ __forceinline__ void stage_half(
    const ushort_t* __restrict__ G, ushort_t* lds_b, int boff,
    int kt, int half, int rowbase, int tid)
{
  // LDS dest region: [buf=kt&1][half] -> 8192 elements (128 rows x 64 k)
  ushort_t* Lb = lds_b + boff + (((kt & 1) << 1) + half) * 8192;
  const int rb = rowbase + (half << 7);
#pragma unroll
  for (int i = 0; i < 2; ++i) {
    const int c = tid + (i << 9);             // chunk id 0..1023
    const int row = c >> 3;
    const int slot = c & 7;
    const int scol = (slot ^ (row & 7)) << 3; // inverse-swizzled source column
    const ushort_t* src = G + (size_t)(rb + row) * 512 + (kt << 6) + scol;
    __builtin_amdgcn_global_load_lds(
        (const __attribute__((address_space(1))) void*)src,
        (__attribute__((address_space(3))) void*)(Lb + ((size_t)c << 3)),
        16, 0, 0);
  }
}

__device__ __forceinline__ void mfma_quad(
    v4f (&accq)[2][4], const v8bf (&af)[2][2], const v8bf (&bq)[4][2])
{
#pragma unroll
  for (int mi = 0; mi < 2; ++mi)
#pragma unroll
    for (int ni = 0; ni < 4; ++ni)
#pragma unroll
      for (int kk = 0; kk < 2; ++kk)
        accq[mi][ni] = __builtin_amdgcn_mfma_f32_16x16x32_bf16(
            af[mi][kk], bq[ni][kk], accq[mi][ni], 0, 0, 0);
}

template<int LDC, int GN, bool ROLL_C, typename OutT>
__global__ __launch_bounds__(512)
__attribute__((amdgpu_waves_per_eu(2, 2)))
void gemm256(
    const ushort_t* __restrict__ A, const ushort_t* __restrict__ BT,
    const float* __restrict__ bias, OutT* __restrict__ C)
{
  extern __shared__ ushort_t lds[];           // 131072 B: A at 0, B at 32768 el

  const int tid = threadIdx.x;
  const int l   = tid & 63;
  const int wv  = tid >> 6;                   // 0..7
  const int wr  = wv >> 1;                    // quadrant row chunk 0..3 (x32)
  const int wc  = wv & 1;                     // quadrant col chunk 0..1 (x64)
  const int fr  = l & 15;
  const int fq  = l >> 4;

  // T1: XCD-aware bijective swizzle (NWG % 8 == 0 for both instantiations)
  constexpr int NWG = GN * 512;               // M tiles = 131072/256 = 512
  const int bid = blockIdx.x;
  const int swz = (bid & 7) * (NWG >> 3) + (bid >> 3);
  const int m0 = (swz / GN) * 256;
  const int n0 = (swz % GN) * 256;

  const int arow = wr * 32 + fr;              // A row within half (mi=0)
  const int brow = wc * 64 + fr;              // B row within half (ni=0)
  const int kswz = (fr & 7) << 3;             // T2 read-side XOR swizzle
  const int kb   = fq << 3;

#define LDA_FRAGS(bufq) do { \
  _Pragma("unroll") for (int mi = 0; mi < 2; ++mi) \
  _Pragma("unroll") for (int kk = 0; kk < 2; ++kk) \
    af[mi][kk] = *(const v8bf*)(lds + (bufq) * 8192 + \
        (arow + mi * 16) * 64 + ((kk * 32 + kb) ^ kswz)); \
} while (0)
#define LDB_FRAGS(qn, bufq) do { \
  _Pragma("unroll") for (int ni = 0; ni < 4; ++ni) \
  _Pragma("unroll") for (int kk = 0; kk < 2; ++kk) \
    bfr[qn][ni][kk] = *(const v8bf*)(lds + 32768 + (bufq) * 8192 + \
        (brow + ni * 16) * 64 + ((kk * 32 + kb) ^ kswz)); \
} while (0)
#define MFMA_PHASE(QM, QN) do { \
  SB(); __builtin_amdgcn_s_barrier(); SB(); \
  __builtin_amdgcn_s_setprio(1); \
  mfma_quad(acc[QM][QN], af, bfr[QN]); \
  __builtin_amdgcn_s_setprio(0); \
  SB(); } while (0)
#define ENDBAR() do { __builtin_amdgcn_s_barrier(); SB(); } while (0)

  v4f acc[2][2][2][4];                        // [Qm][Qn][mi][ni]
#pragma unroll
  for (int a = 0; a < 2; ++a)
#pragma unroll
    for (int b = 0; b < 2; ++b)
#pragma unroll
      for (int m = 0; m < 2; ++m)
#pragma unroll
        for (int n = 0; n < 4; ++n)
          acc[a][b][m][n] = (v4f){0.f, 0.f, 0.f, 0.f};

  // ---- prologue: 6 half-tiles (tile0 complete + tile1 h0s), wait all-but-4
  stage_half(A,  lds, 0,     0, 0, m0, tid);  // A0h0
  stage_half(BT, lds, 32768, 0, 0, n0, tid);  // B0h0
  stage_half(A,  lds, 0,     0, 1, m0, tid);  // A0h1
  stage_half(BT, lds, 32768, 0, 1, n0, tid);  // B0h1
  stage_half(A,  lds, 0,     1, 0, m0, tid);  // A1h0
  stage_half(BT, lds, 32768, 1, 0, n0, tid);  // B1h0
  SB();
  asm volatile("s_waitcnt vmcnt(4)" ::: "memory");  // tile0 landed
  __builtin_amdgcn_s_barrier();
  SB();

  for (int t = 0; t < 4; ++t) {               // 2 K-tiles per iteration
    const bool more = (t < 3);
    const int o = 2 * t + 1;
    v8bf af[2][2];                            // current A half [mi][kk]
    v8bf bfr[2][4][2];                        // both B halves [Qn][ni][kk]

    // ---- phase 1: Q(0,0) of tile 2t (buf0); stage A(buf1,h1) <- tile o
    LDA_FRAGS(0);
    LDB_FRAGS(0, 0);
    stage_half(A, lds, 0, o, 1, m0, tid);
    MFMA_PHASE(0, 0);
    ENDBAR();
    // ---- phase 2: Q(0,1); stage B(buf1,h1) <- tile o
    LDB_FRAGS(1, 1);
    stage_half(BT, lds, 32768, o, 1, n0, tid);
    MFMA_PHASE(0, 1);
    ENDBAR();
    // ---- phase 3: Q(1,0); stage A(buf0,h0) <- tile 2t+2
    LDA_FRAGS(1);
    if (more) stage_half(A, lds, 0, o + 1, 0, m0, tid);
    MFMA_PHASE(1, 0);
    ENDBAR();
    // ---- phase 4: Q(1,1); stage B(buf0,h0) <- tile 2t+2; counted vmcnt
    if (more) stage_half(BT, lds, 32768, o + 1, 0, n0, tid);
    MFMA_PHASE(1, 1);
    if (t == 3) asm volatile("s_waitcnt vmcnt(0)" ::: "memory");
    else        asm volatile("s_waitcnt vmcnt(4)" ::: "memory");
    ENDBAR();
    // ---- phase 5: Q(0,0) of tile o (buf1); stage A(buf0,h1) <- tile 2t+2
    LDA_FRAGS(2);
    LDB_FRAGS(0, 2);
    if (more) stage_half(A, lds, 0, o + 1, 1, m0, tid);
    MFMA_PHASE(0, 0);
    ENDBAR();
    // ---- phase 6: Q(0,1); stage B(buf0,h1) <- tile 2t+2
    LDB_FRAGS(1, 3);
    if (more) stage_half(BT, lds, 32768, o + 1, 1, n0, tid);
    MFMA_PHASE(0, 1);
    ENDBAR();
    // ---- phase 7: Q(1,0); stage A(buf1,h0) <- tile 2t+3
    LDA_FRAGS(3);
    if (more) stage_half(A, lds, 0, o + 2, 0, m0, tid);
    MFMA_PHASE(1, 0);
    ENDBAR();
    // ---- phase 8: Q(1,1); stage B(buf1,h0) <- tile 2t+3; counted vmcnt
    if (more) stage_half(BT, lds, 32768, o + 2, 0, n0, tid);
    MFMA_PHASE(1, 1);
    asm volatile("s_waitcnt vmcnt(4)" ::: "memory");
    ENDBAR();
  }

  // ---- epilogue: C/D layout col = lane&15, row = (lane>>4)*4 + r [m89/m91]
#pragma unroll
  for (int Qm = 0; Qm < 2; ++Qm)
#pragma unroll
    for (int Qn = 0; Qn < 2; ++Qn)
#pragma unroll
      for (int mi = 0; mi < 2; ++mi)
#pragma unroll
        for (int ni = 0; ni < 4; ++ni) {
          const int col = n0 + Qn * 128 + wc * 64 + ni * 16 + fr;
          const float bv = bias[col];
#pragma unroll
          for (int r = 0; r < 4; ++r) {
            int row = m0 + Qm * 128 + wr * 32 + mi * 16 + fq * 4 + r;
            if (ROLL_C) row = (row & ~4095) | ((row + 4) & 4095);
            const float val = acc[Qm][Qn][mi][ni][r] + bv;
            if constexpr (std::is_same_v<OutT, float>)
              C[(size_t)row * LDC + col] = val;
            else
              C[(size_t)row * LDC + col] = f2bf(val);
          }
        }

#undef LDA_FRAGS
#undef LDB_FRAGS
#undef MFMA_PHASE
#undef ENDBAR
}

// ---------------- attention: one wave per (batch, window, head) --------------
// qkv layout: [B*L][1536] rolled rows; cols 0..511=Q, 512..1023=K, 1024..1535=V
__device__ __forceinline__ void unpack8(uint4 v, float* f) {
  f[0] = __uint_as_float(v.x << 16); f[1] = __uint_as_float(v.x & 0xffff0000u);
  f[2] = __uint_as_float(v.y << 16); f[3] = __uint_as_float(v.y & 0xffff0000u);
  f[4] = __uint_as_float(v.z << 16); f[5] = __uint_as_float(v.z & 0xffff0000u);
  f[6] = __uint_as_float(v.w << 16); f[7] = __uint_as_float(v.w & 0xffff0000u);
}

__global__ __launch_bounds__(256) void attn_kernel(
    const ushort_t* __restrict__ qkv, const float* __restrict__ bias_table,
    ushort_t* __restrict__ attout)
{
  __shared__ float btab[120];                 // (2S-1) x H fp32
  if (threadIdx.x < 120) btab[threadIdx.x] = bias_table[threadIdx.x];
  __syncthreads();

  const int l  = threadIdx.x & 63;
  const int wv = threadIdx.x >> 6;
  const int u  = blockIdx.x * 4 + wv;         // window-head id
  const int b  = u >> 12;                     // NW*H = 4096
  const int w  = (u >> 3) & 511;
  const int h  = u & 7;
  const int i  = l >> 3;                      // query row in window
  const int c  = l & 7;                       // 8-element d-chunk

  const size_t rowi = (size_t)(b << 12) + (w << 3) + i;
  const ushort_t* pq = qkv + rowi * 1536 + h * 64 + c * 8;
  uint4 q8 = *(const uint4*)pq;
  uint4 k8 = *(const uint4*)(pq + 512);
  uint4 v8 = *(const uint4*)(pq + 1024);

  float qf[8];
  unpack8(q8, qf);

  // energy[i][j], j = (i+t)&7 held in e[t]; rotation via shfl (l+8t)&63
  float e[8];
#pragma unroll
  for (int t = 0; t < 8; ++t) {
    const int src = (l + 8 * t) & 63;
    uint4 kc;
    kc.x = __shfl((int)k8.x, src); kc.y = __shfl((int)k8.y, src);
    kc.z = __shfl((int)k8.z, src); kc.w = __shfl((int)k8.w, src);
    float kf[8]; unpack8(kc, kf);
    float s = 0.f;
#pragma unroll
    for (int d = 0; d < 8; ++d) s = fmaf(qf[d], kf[d], s);
    s += __shfl_xor(s, 1);                    // butterfly over c (3 steps)
    s += __shfl_xor(s, 2);
    s += __shfl_xor(s, 4);
    e[t] = s;
  }

  const float scale = 0.044194173824159216f;  // 1/sqrt(C=512)
#pragma unroll
  for (int t = 0; t < 8; ++t) {
    const int j = (i + t) & 7;
    float ev = e[t] * scale + btab[(j - i + 7) * 8 + h];
    if (w == 511 && ((i < 4) != (j < 4))) ev -= 100.f;  // shift mask
    e[t] = ev;
  }

  float mx = e[0];
#pragma unroll
  for (int t = 1; t < 8; ++t) mx = fmaxf(mx, e[t]);
  float p[8], sum = 0.f;
#pragma unroll
  for (int t = 0; t < 8; ++t) { p[t] = __expf(e[t] - mx); sum += p[t]; }
  const float inv = __fdividef(1.f, sum);

  float of[8] = {0.f, 0.f, 0.f, 0.f, 0.f, 0.f, 0.f, 0.f};
#pragma unroll
  for (int t = 0; t < 8; ++t) {
    const int src = (l + 8 * t) & 63;
    uint4 vc;
    vc.x = __shfl((int)v8.x, src); vc.y = __shfl((int)v8.y, src);
    vc.z = __shfl((int)v8.z, src); vc.w = __shfl((int)v8.w, src);
    float vf[8]; unpack8(vc, vf);
    const float a = p[t] * inv;
#pragma unroll
    for (int d = 0; d < 8; ++d) of[d] = fmaf(a, vf[d], of[d]);
  }

  uint4 o;
  o.x = (unsigned)f2bf(of[0]) | ((unsigned)f2bf(of[1]) << 16);
  o.y = (unsigned)f2bf(of[2]) | ((unsigned)f2bf(of[3]) << 16);
  o.z = (unsigned)f2bf(of[4]) | ((unsigned)f2bf(of[5]) << 16);
  o.w = (unsigned)f2bf(of[6]) | ((unsigned)f2bf(of[7]) << 16);
  *(uint4*)(attout + rowi * 512 + h * 64 + c * 8) = o;
}

// ---------------- launcher ---------------------------------------------------
extern "C" void kernel_launch(void* const* d_in, const int* in_sizes, int n_in,
                              void* d_out, int out_size, void* d_ws, size_t ws_size,
                              hipStream_t stream) {
  (void)in_sizes; (void)n_in; (void)out_size; (void)ws_size;
  const float* x  = (const float*)d_in[0];
  const float* Wq = (const float*)d_in[1];
  const float* bq = (const float*)d_in[2];
  const float* Wk = (const float*)d_in[3];
  const float* bk = (const float*)d_in[4];
  const float* Wv = (const float*)d_in[5];
  const float* bv = (const float*)d_in[6];
  const float* Wp = (const float*)d_in[7];
  const float* bp = (const float*)d_in[8];
  const float* bt = (const float*)d_in[9];

  char* ws = (char*)d_ws;
  ushort_t* qkv    = (ushort_t*)(ws);                    // 131072*1536*2 = 402,653,184
  ushort_t* xb     = (ushort_t*)(ws + 402653184ull);     // 131072*512*2  = 134,217,728
  ushort_t* attout = xb;                                 // reuse: xb dead after QKV GEMM
  ushort_t* WTqkv  = (ushort_t*)(ws + 536870912ull);     // 1536*512*2
  ushort_t* WTp    = (ushort_t*)(ws + 538443776ull);     // 512*512*2
  float*    bqkvf  = (float*)  (ws + 538968064ull);      // 1536*4

  prep_kernel<<<4103, 256, 0, stream>>>(Wq, Wk, Wv, Wp, bq, bk, bv,
                                        WTqkv, WTp, bqkvf);
  // fp32 -> bf16 with roll(x,-4) folded in
  convert_roll_kernel<<<32768, 256, 0, stream>>>(x, xb);
  // QKV projection (bf16 out): M=131072, N=1536, K=512 -> 3072 blocks
  gemm256<1536, 6, false, ushort_t><<<3072, 512, 131072, stream>>>(
      xb, WTqkv, bqkvf, qkv);
  // windowed attention
  attn_kernel<<<32768, 256, 0, stream>>>(qkv, bt, attout);
  // output projection, fp32 out, roll(+4) folded into C-row remap
  gemm256<512, 2, true, float><<<1024, 512, 131072, stream>>>(
      attout, WTp, bp, (float*)d_out);
}